// Round 5
// baseline (607.634 us; speedup 1.0000x reference)
//
#include <hip/hip_runtime.h>
#include <hip/hip_cooperative_groups.h>
#include <math.h>

namespace cg = cooperative_groups;

// ---------------------------------------------------------------------------
// YOLOv5 head, ONE cooperative kernel (R5).
// R4 failure: 59.4 KB static LDS capped residency at 2 blocks/CU for ALL
// phases; P1 (42 MB stream) ran at 350 GB/s (= 8 waves/CU x 16 x 4 B
// in-flight / 900 cy), 120+ us. R5: P1 rebuilt as float4 x split-K-32
// (16 B/lane loads, 89600 tasks, atomicAdd partials), LDS union shrunk to
// 30 KB (NMS CAP2=1024 >= reference top-1000 cap), launch_bounds(256,4)
// => 4 blocks/CU co-resident, grid 960.
// Phases: A zero+pack WT -> B dense obj GEMV -> C threshold -> D per-cand
// 85-row scoring -> E per-image greedy NMS. grid.sync() between phases.
// ---------------------------------------------------------------------------

#define IMG_F 640.0f

// ws layout (units: 4-byte words)
#define LOGITS_F 0               // 201600 floats: obj logits [n][25200]
#define N_LOGITS 201600          //   n*25200 + aoff(level) + s*3 + a
#define WT_F     201600          // transposed weights [level][a][c][128]
#define N_WT     344064          //   row l innermost, pad l>=85 = 0
#define WT_L0    0               // 3*128*128
#define WT_L1    49152           // 3*256*128
#define WT_L2    147456          // 3*512*128
#define CAND_F   (WT_F + N_WT)   // CAP1 x {code:int, obj:float}
#define CAP1     4096
#define CNT_F    (CAND_F + CAP1*2)  // [0]=cand count, [1..8]=per-image
#define IMGBUF_F (CNT_F + 16)       // 8 x CAP2 x 6 floats
#define CAP2     1024
// total ~= 2.4 MB of d_ws

#define LOGIT_T (-2.1972245773362196f)   // logit(0.1)
#define NBLK    960
#define NTASK   89600            // 51200 (L0,KB4) + 25600 (L1,KB8) + 12800 (L2,KB16)

__constant__ float d_anch[3][3][2] = {
  {{6.1f,8.1f},{20.6f,12.6f},{11.2f,23.7f}},
  {{36.2f,26.8f},{25.9f,57.2f},{57.8f,47.9f}},
  {{122.1f,78.3f},{73.7f,143.8f},{236.1f,213.1f}},
};
__constant__ float d_stridec[3] = {8.f,16.f,32.f};

union ShMem {
  float fcol[4][512];                   // D: per-wave feature column (8 KB)
  struct {
    float bx1[CAP2], by1[CAP2], bx2[CAP2], by2[CAP2], bsc[CAP2], blb[CAP2];
    int   bval[CAP2];
    float rs[256];
    int   ri[256];
  } nms;                                // E: 30 KB
};

// -------- D helper: one wave per candidate, lane = output row --------------
template<int C, int HW, int Wd>
__device__ __forceinline__ void k2_cand(
    int level, int n, int a, int s, float obj,
    const float* __restrict__ f, const float* __restrict__ wTl,
    const float* __restrict__ bb, float* __restrict__ ws,
    float* __restrict__ fc, int lane) {
  #pragma unroll
  for (int j = 0; j < C / 64; ++j)
    fc[lane + 64 * j] = f[((size_t)(n * C + lane + 64 * j)) * HW + s];
  const float* wA = wTl + (size_t)a * C * 128;
  float acc1 = 0.f, acc2 = 0.f;          // rows: lane, 64+lane (pad rows = 0)
  #pragma unroll 8
  for (int c = 0; c < C; ++c) {
    float fv = fc[c];                    // LDS broadcast, conflict-free
    const float* wl = wA + c * 128;
    acc1 = fmaf(fv, wl[lane], acc1);     // coalesced 64 consecutive floats
    acc2 = fmaf(fv, wl[64 + lane], acc2);
  }
  acc1 += bb[a * 85 + lane];             // rows 0..63 all valid
  float sig1 = 1.f / (1.f + expf(-acc1));
  float sig2 = 0.f;
  if (lane < 21) {                       // rows 64..84
    acc2 += bb[a * 85 + 64 + lane];
    sig2 = 1.f / (1.f + expf(-acc2));
  }
  float p0 = __shfl(sig1, 0, 64), p1 = __shfl(sig1, 1, 64);
  float p2 = __shfl(sig1, 2, 64), p3 = __shfl(sig1, 3, 64);
  int gx = s % Wd, gy = s / Wd;
  float st = d_stridec[level];
  float cx = (2.f * p0 - 0.5f + (float)gx) * st;
  float cy = (2.f * p1 - 0.5f + (float)gy) * st;
  float bw = 4.f * p2 * p2 * d_anch[level][a][0];
  float bh = 4.f * p3 * p3 * d_anch[level][a][1];
  float x1 = fminf(fmaxf(cx - bw * 0.5f, 0.f), IMG_F);
  float y1 = fminf(fmaxf(cy - bh * 0.5f, 0.f), IMG_F);
  float x2 = fminf(fmaxf(cx + bw * 0.5f, 0.f), IMG_F);
  float y2 = fminf(fmaxf(cy + bh * 0.5f, 0.f), IMG_F);
  #pragma unroll
  for (int half = 0; half < 2; ++half) {
    bool on = half == 0 ? (lane >= 5) : (lane < 21);
    float sc = obj * (half == 0 ? sig1 : sig2);
    int cls = half == 0 ? (lane - 5) : (59 + lane);
    if (on && sc > 0.1f) {
      int p = atomicAdd((int*)ws + CNT_F + 1 + n, 1);
      if (p < CAP2) {
        float* dst = ws + IMGBUF_F + ((size_t)(n * CAP2 + p)) * 6;
        dst[0] = x1; dst[1] = y1; dst[2] = x2; dst[3] = y2;
        dst[4] = sc; dst[5] = (float)cls;
      }
    }
  }
}

__global__ __launch_bounds__(256, 4) void fused_yolo(
    const float* __restrict__ f0, const float* __restrict__ f1,
    const float* __restrict__ f2,
    const float* __restrict__ w0, const float* __restrict__ w1,
    const float* __restrict__ w2,
    const float* __restrict__ b0, const float* __restrict__ b1,
    const float* __restrict__ b2,
    const float* __restrict__ sfp,
    float* __restrict__ ws, float* __restrict__ out) {
  __shared__ ShMem sh;
  cg::grid_group grid = cg::this_grid();
  const int tid = threadIdx.x;
  const int gid0 = blockIdx.x * 256 + tid;
  const int gsz = NBLK * 256;

  // ---------------- A: zero logits/out/counters + pack WT ------------------
  for (int i = gid0; i < N_WT; i += gsz) {
    if (i < N_LOGITS) ws[LOGITS_F + i] = 0.f;
    if (i < 4800)     out[i] = 0.f;      // harness poisons d_out each call
    if (i < 16)       ((int*)ws)[CNT_F + i] = 0;
    // transposed weights wT[level][a][c][128], row l innermost, pad -> 0
    int C, i2; const float* w;
    if (i < WT_L1)      { C = 128; i2 = i;         w = w0; }
    else if (i < WT_L2) { C = 256; i2 = i - WT_L1; w = w1; }
    else                { C = 512; i2 = i - WT_L2; w = w2; }
    int a = i2 / (C * 128);
    int r = i2 - a * (C * 128);
    int c = r >> 7, l = r & 127;
    ws[WT_F + i] = (l < 85) ? w[(size_t)(a * 85 + l) * C + c] : 0.f;
  }
  grid.sync();

  // ---------------- B: dense obj-logit GEMV (float4 x split-K-32) ----------
  // task = (4-position quad) x (32-channel chunk); 12 atomicAdd partials.
  for (int t = gid0; t < NTASK; t += gsz) {
    int quad, kc, C, HW, aoff;
    const float *f, *w;
    if (t < 51200)      { quad = t >> 2, kc = t & 3;  C = 128; HW = 6400; aoff = 0;     f = f0; w = w0; }
    else if (t < 76800) { int u = t - 51200; quad = u >> 3, kc = u & 7;  C = 256; HW = 1600; aoff = 19200; f = f1; w = w1; }
    else                { int u = t - 76800; quad = u >> 4, kc = u & 15; C = 512; HW = 400;  aoff = 24000; f = f2; w = w2; }
    int qpi = HW >> 2;
    int n = quad / qpi;
    int sq = (quad - n * qpi) << 2;
    const float* fp = f + ((size_t)(n * C + kc * 32)) * HW + sq;
    const float* wobj = w + 4 * C + kc * 32;          // row a*85+4, chunk base
    float acc[3][4] = {{0.f,0.f,0.f,0.f},{0.f,0.f,0.f,0.f},{0.f,0.f,0.f,0.f}};
    #pragma unroll 8
    for (int c = 0; c < 32; ++c) {
      float4 v = *(const float4*)(fp + (size_t)c * HW);   // 16 B/lane coalesced
      float wa0 = wobj[c];                 // L1/L2-hot broadcast-ish
      float wa1 = wobj[85 * C + c];
      float wa2 = wobj[170 * C + c];
      acc[0][0] = fmaf(v.x, wa0, acc[0][0]); acc[0][1] = fmaf(v.y, wa0, acc[0][1]);
      acc[0][2] = fmaf(v.z, wa0, acc[0][2]); acc[0][3] = fmaf(v.w, wa0, acc[0][3]);
      acc[1][0] = fmaf(v.x, wa1, acc[1][0]); acc[1][1] = fmaf(v.y, wa1, acc[1][1]);
      acc[1][2] = fmaf(v.z, wa1, acc[1][2]); acc[1][3] = fmaf(v.w, wa1, acc[1][3]);
      acc[2][0] = fmaf(v.x, wa2, acc[2][0]); acc[2][1] = fmaf(v.y, wa2, acc[2][1]);
      acc[2][2] = fmaf(v.z, wa2, acc[2][2]); acc[2][3] = fmaf(v.w, wa2, acc[2][3]);
    }
    float* lg = ws + LOGITS_F + (size_t)n * 25200 + aoff + sq * 3;
    #pragma unroll
    for (int a = 0; a < 3; ++a)
      #pragma unroll
      for (int p = 0; p < 4; ++p)
        atomicAdd(lg + p * 3 + a, acc[a][p]);
  }
  grid.sync();

  // ---------------- C: bias + sigmoid threshold + candidate push -----------
  for (int i = gid0; i < N_LOGITS; i += gsz) {
    int n = i / 25200, r = i - n * 25200;
    int level, roff;
    if (r < 19200)      { level = 0; roff = r; }
    else if (r < 24000) { level = 1; roff = r - 19200; }
    else                { level = 2; roff = r - 24000; }
    int s = roff / 3, a = roff - s * 3;
    const float* bb = (level == 0) ? b0 : (level == 1) ? b1 : b2;
    float logit = ws[LOGITS_F + i] + bb[a * 85 + 4];
    if (logit > LOGIT_T) {
      float obj = 1.f / (1.f + expf(-logit));
      int idx = atomicAdd((int*)ws + CNT_F, 1);
      if (idx < CAP1) {
        int* cd = (int*)ws + CAND_F + idx * 2;
        cd[0] = (n << 24) | (level << 20) | (a << 16) | s;
        ((float*)cd)[1] = obj;
      }
    }
  }
  grid.sync();

  // ---------------- D: per-candidate 85-row scoring ------------------------
  {
    int wv = tid >> 6, lane = tid & 63;
    int count = min(((int*)ws)[CNT_F], CAP1);
    int nslots = NBLK * 4;
    for (int cid = blockIdx.x * 4 + wv; cid < count; cid += nslots) {
      int* cd = (int*)ws + CAND_F + cid * 2;
      int code = cd[0]; float obj = ((float*)cd)[1];
      int n = code >> 24, level = (code >> 20) & 15, a = (code >> 16) & 3, s = code & 0xFFFF;
      if (level == 0)
        k2_cand<128, 6400, 80>(0, n, a, s, obj, f0, ws + WT_F + WT_L0, b0, ws, sh.fcol[wv], lane);
      else if (level == 1)
        k2_cand<256, 1600, 40>(1, n, a, s, obj, f1, ws + WT_F + WT_L1, b1, ws, sh.fcol[wv], lane);
      else
        k2_cand<512, 400, 20>(2, n, a, s, obj, f2, ws + WT_F + WT_L2, b2, ws, sh.fcol[wv], lane);
    }
  }
  grid.sync();

  // ---------------- E: per-image greedy NMS --------------------------------
  if (blockIdx.x < 8) {
    int n = blockIdx.x;
    int cnt = min(((const int*)ws)[CNT_F + 1 + n], CAP2);
    for (int i = tid; i < cnt; i += 256) {
      const float* src = ws + IMGBUF_F + ((size_t)(n * CAP2 + i)) * 6;
      sh.nms.bx1[i] = src[0]; sh.nms.by1[i] = src[1];
      sh.nms.bx2[i] = src[2]; sh.nms.by2[i] = src[3];
      sh.nms.bsc[i] = src[4]; sh.nms.blb[i] = src[5];
      sh.nms.bval[i] = 1;
    }
    __syncthreads();
    float sf = sfp[n];
    for (int it = 0; it < 100; ++it) {
      float best = -1.f; int bi = -1;
      for (int i = tid; i < cnt; i += 256)
        if (sh.nms.bval[i] && sh.nms.bsc[i] > best) { best = sh.nms.bsc[i]; bi = i; }
      sh.nms.rs[tid] = best; sh.nms.ri[tid] = bi;
      __syncthreads();
      for (int off = 128; off > 0; off >>= 1) {
        if (tid < off && sh.nms.rs[tid + off] > sh.nms.rs[tid]) {
          sh.nms.rs[tid] = sh.nms.rs[tid + off];
          sh.nms.ri[tid] = sh.nms.ri[tid + off];
        }
        __syncthreads();
      }
      int wi = sh.nms.ri[0]; float wsc = sh.nms.rs[0];
      if (wi < 0) break;                  // uniform: no valid left, rows stay 0
      if (tid == 0) {
        float* o = out + (size_t)(n * 100 + it) * 6;
        o[0] = sh.nms.bx1[wi] / sf; o[1] = sh.nms.by1[wi] / sf;
        o[2] = sh.nms.bx2[wi] / sf; o[3] = sh.nms.by2[wi] / sf;
        o[4] = wsc;                 o[5] = sh.nms.blb[wi];
      }
      float ofw = sh.nms.blb[wi] * IMG_F;
      float wx1 = sh.nms.bx1[wi] + ofw, wy1 = sh.nms.by1[wi] + ofw;
      float wx2 = sh.nms.bx2[wi] + ofw, wy2 = sh.nms.by2[wi] + ofw;
      float wa = (wx2 - wx1) * (wy2 - wy1);
      for (int i = tid; i < cnt; i += 256) {
        if (sh.nms.bval[i]) {
          float o2 = sh.nms.blb[i] * IMG_F;
          float x1 = sh.nms.bx1[i] + o2, y1 = sh.nms.by1[i] + o2;
          float x2 = sh.nms.bx2[i] + o2, y2 = sh.nms.by2[i] + o2;
          float iw = fmaxf(fminf(wx2, x2) - fmaxf(wx1, x1), 0.f);
          float ih = fmaxf(fminf(wy2, y2) - fmaxf(wy1, y1), 0.f);
          float inter = iw * ih;
          float area = (x2 - x1) * (y2 - y1);
          float iou = inter / (wa + area - inter + 1e-7f);
          if (iou > 0.6f) sh.nms.bval[i] = 0;
        }
      }
      if (tid == 0) sh.nms.bval[wi] = 0;
      __syncthreads();
    }
  }
}

// ---------------------------------------------------------------------------
extern "C" void kernel_launch(void* const* d_in, const int* in_sizes, int n_in,
                              void* d_out, int out_size, void* d_ws, size_t ws_size,
                              hipStream_t stream) {
  // setup_inputs() dict order: f0,w0,b0, f1,w1,b1, f2,w2,b2, scale_factors
  const float* f0 = (const float*)d_in[0];
  const float* w0 = (const float*)d_in[1];
  const float* b0 = (const float*)d_in[2];
  const float* f1 = (const float*)d_in[3];
  const float* w1 = (const float*)d_in[4];
  const float* b1 = (const float*)d_in[5];
  const float* f2 = (const float*)d_in[6];
  const float* w2 = (const float*)d_in[7];
  const float* b2 = (const float*)d_in[8];
  const float* sf = (const float*)d_in[9];
  float* out = (float*)d_out;
  float* ws  = (float*)d_ws;    // needs ~2.4 MB

  void* kargs[] = {
    (void*)&f0, (void*)&f1, (void*)&f2,
    (void*)&w0, (void*)&w1, (void*)&w2,
    (void*)&b0, (void*)&b1, (void*)&b2,
    (void*)&sf, (void*)&ws, (void*)&out,
  };
  hipLaunchCooperativeKernel((const void*)fused_yolo, dim3(NBLK), dim3(256),
                             kargs, 0, stream);
}

// Round 6
// 128.678 us; speedup vs baseline: 4.7221x; 4.7221x over previous
//
#include <hip/hip_runtime.h>
#include <math.h>

// ---------------------------------------------------------------------------
// YOLOv5 head (R6): back to SEPARATE kernel launches.
// R4/R5 post-mortem: cooperative grid.sync() spin-polls with device-scope
// acquire loads -> continuous per-XCD L2 invalidation; both fused kernels ran
// at a constant ~150 GB/s with VALUBusy <1% and time scaling with resident
// waves. Plain stream-ordered kernels (R3, 134.9 us) beat it by 2-4x.
// R6 pipeline (4 kernels):
//   KA: pack transposed weights WT + zero out/counters
//   KB: dense obj-logit GEMV, K split ACROSS THREADS within a block + LDS
//       reduction -> sole writer per position -> threshold fused for ALL
//       levels (no logits buffer, no split-K atomics, no k1b kernel).
//       Uniform work: every thread 16 float4 loads; 700 equal blocks.
//   KC: per-candidate 85-row scoring (lane=row, coalesced WT) [R3-proven]
//   KD: per-image greedy NMS [R3-proven]
// ---------------------------------------------------------------------------

#define IMG_F 640.0f

// ws layout (units: 4-byte words)
#define WT_F     0               // transposed weights [level][a][c][128]
#define N_WT     344064          //   row l innermost, pad l>=85 = 0
#define WT_L0    0               // 3*128*128
#define WT_L1    49152           // 3*256*128
#define WT_L2    147456          // 3*512*128
#define CAND_F   344064          // CAP1 x {code:int, obj:float}
#define CAP1     4096
#define CNT_F    (CAND_F + CAP1*2)   // [0]=cand count, [1..8]=per-image
#define IMGBUF_F (CNT_F + 16)        // 8 x CAP2 x 6 floats
#define CAP2     2048
// total = 450576 words ~= 1.8 MB of d_ws

#define LOGIT_T (-2.1972245773362196f)   // logit(0.1)

__constant__ float d_anch[3][3][2] = {
  {{6.1f,8.1f},{20.6f,12.6f},{11.2f,23.7f}},
  {{36.2f,26.8f},{25.9f,57.2f},{57.8f,47.9f}},
  {{122.1f,78.3f},{73.7f,143.8f},{236.1f,213.1f}},
};
__constant__ float d_stridec[3] = {8.f,16.f,32.f};

// ---------------------------------------------------------------- KA: init --
__global__ __launch_bounds__(256) void ka_init(
    float* __restrict__ ws, float* __restrict__ out,
    const float* __restrict__ w0, const float* __restrict__ w1,
    const float* __restrict__ w2) {
  int i = blockIdx.x * 256 + threadIdx.x;
  if (i < 4800) out[i] = 0.f;            // harness poisons d_out each call
  if (i < 16)   ((int*)ws)[CNT_F + i] = 0;
  if (i < N_WT) {
    // transposed weights wT[level][a][c][128], row l innermost, pad -> 0.
    // writes coalesced (l fastest); scattered reads absorbed by L2.
    int C, i2; const float* w;
    if (i < WT_L1)      { C = 128; i2 = i;         w = w0; }
    else if (i < WT_L2) { C = 256; i2 = i - WT_L1; w = w1; }
    else                { C = 512; i2 = i - WT_L2; w = w2; }
    int a = i2 / (C * 128);
    int r = i2 - a * (C * 128);
    int c = r >> 7, l = r & 127;
    ws[WT_F + i] = (l < 85) ? w[(size_t)(a * 85 + l) * C + c] : 0.f;
  }
}

// ------------- KB: dense obj GEMV, in-block K-split + LDS reduce -----------
// Block covers Q quads (4 consecutive positions each) x full K; thread
// (q, slice) loads 16 channels x float4. Sole writer per position =>
// threshold + candidate push fused for all levels.
//   L0: blocks [0,400):   Q=32, S=8   (C=128, HW=6400)
//   L1: blocks [400,600): Q=16, S=16  (C=256, HW=1600)
//   L2: blocks [600,700): Q=8,  S=32  (C=512, HW=400)
__global__ __launch_bounds__(256) void kb_obj(
    const float* __restrict__ f0, const float* __restrict__ f1,
    const float* __restrict__ f2,
    const float* __restrict__ w0, const float* __restrict__ w1,
    const float* __restrict__ w2,
    const float* __restrict__ b0, const float* __restrict__ b1,
    const float* __restrict__ b2, float* __restrict__ ws) {
  __shared__ float red[3104];            // max S*(Q*12+1) over levels
  int b = blockIdx.x, t = threadIdx.x;
  int level, Q, lq, S, bq0, C, HW;
  const float *f, *w, *bb;
  if (b < 400)      { level = 0; Q = 32; lq = 5; S = 8;  bq0 = b * 32;         C = 128; HW = 6400; f = f0; w = w0; bb = b0; }
  else if (b < 600) { level = 1; Q = 16; lq = 4; S = 16; bq0 = (b - 400) * 16; C = 256; HW = 1600; f = f1; w = w1; bb = b1; }
  else              { level = 2; Q = 8;  lq = 3; S = 32; bq0 = (b - 600) * 8;  C = 512; HW = 400;  f = f2; w = w2; bb = b2; }
  int q = t & (Q - 1), sl = t >> lq;
  int qpi = HW >> 2;
  int gq = bq0 + q;
  int n = gq / qpi;
  int sq = (gq - n * qpi) << 2;
  int kbase = sl * 16;                   // C/S == 16 for all levels
  const float* fp = f + ((size_t)(n * C + kbase)) * HW + sq;
  const float* wp = w + 4 * C + kbase;   // obj row for a=0; a=1:+85C; a=2:+170C
  float acc[3][4] = {{0.f,0.f,0.f,0.f},{0.f,0.f,0.f,0.f},{0.f,0.f,0.f,0.f}};
  #pragma unroll
  for (int c = 0; c < 16; ++c) {
    float4 v = *(const float4*)(fp + (size_t)c * HW);   // 16 B/lane coalesced
    float wa0 = wp[c];
    float wa1 = wp[85 * C + c];
    float wa2 = wp[170 * C + c];
    acc[0][0] = fmaf(v.x, wa0, acc[0][0]); acc[0][1] = fmaf(v.y, wa0, acc[0][1]);
    acc[0][2] = fmaf(v.z, wa0, acc[0][2]); acc[0][3] = fmaf(v.w, wa0, acc[0][3]);
    acc[1][0] = fmaf(v.x, wa1, acc[1][0]); acc[1][1] = fmaf(v.y, wa1, acc[1][1]);
    acc[1][2] = fmaf(v.z, wa1, acc[1][2]); acc[1][3] = fmaf(v.w, wa1, acc[1][3]);
    acc[2][0] = fmaf(v.x, wa2, acc[2][0]); acc[2][1] = fmaf(v.y, wa2, acc[2][1]);
    acc[2][2] = fmaf(v.z, wa2, acc[2][2]); acc[2][3] = fmaf(v.w, wa2, acc[2][3]);
  }
  // LDS: red[sl*(Q*12+1) + q*12 + a*4+p]; +1 pad => slice stride is odd,
  // conflict-free strided reduction reads.
  int stride = Q * 12 + 1;
  int base = sl * stride + q * 12;
  #pragma unroll
  for (int a = 0; a < 3; ++a)
    #pragma unroll
    for (int p = 0; p < 4; ++p)
      red[base + a * 4 + p] = acc[a][p];
  __syncthreads();
  for (int r = t; r < Q * 12; r += 256) {
    int qq = r / 12, ap = r - qq * 12;
    int a = ap >> 2, p = ap & 3;
    float sum = 0.f;
    for (int s2 = 0; s2 < S; ++s2) sum += red[s2 * stride + qq * 12 + ap];
    float logit = sum + bb[a * 85 + 4];
    if (logit > LOGIT_T) {               // sigmoid(x)>0.1 <=> x>logit(0.1)
      float obj = 1.f / (1.f + expf(-logit));
      int gq2 = bq0 + qq;
      int n2 = gq2 / qpi;
      int s = ((gq2 - n2 * qpi) << 2) + p;
      int idx = atomicAdd((int*)ws + CNT_F, 1);
      if (idx < CAP1) {
        int* cd = (int*)ws + CAND_F + idx * 2;
        cd[0] = (n2 << 24) | (level << 20) | (a << 16) | s;
        ((float*)cd)[1] = obj;
      }
    }
  }
}

// -------- KC: one wave per candidate, lane = output row, coalesced WT ------
template<int C, int HW, int Wd>
__device__ __forceinline__ void kc_cand(
    int level, int n, int a, int s, float obj,
    const float* __restrict__ f, const float* __restrict__ wTl,
    const float* __restrict__ bb, float* __restrict__ ws,
    float* __restrict__ fc, int lane) {
  #pragma unroll
  for (int j = 0; j < C / 64; ++j)
    fc[lane + 64 * j] = f[((size_t)(n * C + lane + 64 * j)) * HW + s];
  const float* wA = wTl + (size_t)a * C * 128;
  float acc1 = 0.f, acc2 = 0.f;          // rows: lane, 64+lane (pad rows = 0)
  #pragma unroll 8
  for (int c = 0; c < C; ++c) {
    float fv = fc[c];                    // LDS broadcast, conflict-free
    const float* wl = wA + c * 128;
    acc1 = fmaf(fv, wl[lane], acc1);     // coalesced 64 consecutive floats
    acc2 = fmaf(fv, wl[64 + lane], acc2);
  }
  acc1 += bb[a * 85 + lane];             // rows 0..63 all valid
  float sig1 = 1.f / (1.f + expf(-acc1));
  float sig2 = 0.f;
  if (lane < 21) {                       // rows 64..84
    acc2 += bb[a * 85 + 64 + lane];
    sig2 = 1.f / (1.f + expf(-acc2));
  }
  float p0 = __shfl(sig1, 0, 64), p1 = __shfl(sig1, 1, 64);
  float p2 = __shfl(sig1, 2, 64), p3 = __shfl(sig1, 3, 64);
  int gx = s % Wd, gy = s / Wd;
  float st = d_stridec[level];
  float cx = (2.f * p0 - 0.5f + (float)gx) * st;
  float cy = (2.f * p1 - 0.5f + (float)gy) * st;
  float bw = 4.f * p2 * p2 * d_anch[level][a][0];
  float bh = 4.f * p3 * p3 * d_anch[level][a][1];
  float x1 = fminf(fmaxf(cx - bw * 0.5f, 0.f), IMG_F);
  float y1 = fminf(fmaxf(cy - bh * 0.5f, 0.f), IMG_F);
  float x2 = fminf(fmaxf(cx + bw * 0.5f, 0.f), IMG_F);
  float y2 = fminf(fmaxf(cy + bh * 0.5f, 0.f), IMG_F);
  #pragma unroll
  for (int half = 0; half < 2; ++half) {
    bool on = half == 0 ? (lane >= 5) : (lane < 21);
    float sc = obj * (half == 0 ? sig1 : sig2);
    int cls = half == 0 ? (lane - 5) : (59 + lane);
    if (on && sc > 0.1f) {
      int p = atomicAdd((int*)ws + CNT_F + 1 + n, 1);
      if (p < CAP2) {
        float* dst = ws + IMGBUF_F + ((size_t)(n * CAP2 + p)) * 6;
        dst[0] = x1; dst[1] = y1; dst[2] = x2; dst[3] = y2;
        dst[4] = sc; dst[5] = (float)cls;
      }
    }
  }
}

__global__ __launch_bounds__(256) void kc_score(
    const float* __restrict__ f0, const float* __restrict__ f1,
    const float* __restrict__ f2,
    const float* __restrict__ b0, const float* __restrict__ b1,
    const float* __restrict__ b2, float* __restrict__ ws) {
  __shared__ float fcol[4][512];
  int wv = threadIdx.x >> 6, lane = threadIdx.x & 63;
  int count = min(((int*)ws)[CNT_F], CAP1);
  int nslots = gridDim.x * 4;
  for (int cid = blockIdx.x * 4 + wv; cid < count; cid += nslots) {
    int* cd = (int*)ws + CAND_F + cid * 2;
    int code = cd[0]; float obj = ((float*)cd)[1];
    int n = code >> 24, level = (code >> 20) & 15, a = (code >> 16) & 3, s = code & 0xFFFF;
    if (level == 0)
      kc_cand<128, 6400, 80>(0, n, a, s, obj, f0, ws + WT_F + WT_L0, b0, ws, fcol[wv], lane);
    else if (level == 1)
      kc_cand<256, 1600, 40>(1, n, a, s, obj, f1, ws + WT_F + WT_L1, b1, ws, fcol[wv], lane);
    else
      kc_cand<512, 400, 20>(2, n, a, s, obj, f2, ws + WT_F + WT_L2, b2, ws, fcol[wv], lane);
  }
}

// ------------------------------------------ KD: per-image greedy NMS -------
__global__ __launch_bounds__(256) void kd_nms(
    const float* __restrict__ ws, float* __restrict__ out,
    const float* __restrict__ sfp) {
  __shared__ float bx1[CAP2], by1[CAP2], bx2[CAP2], by2[CAP2], bsc[CAP2], blb[CAP2];
  __shared__ int bval[CAP2];
  __shared__ float rs[256];
  __shared__ int ri[256];
  int n = blockIdx.x, tid = threadIdx.x;
  int cnt = min(((const int*)ws)[CNT_F + 1 + n], CAP2);
  for (int i = tid; i < cnt; i += 256) {
    const float* src = ws + IMGBUF_F + ((size_t)(n * CAP2 + i)) * 6;
    bx1[i] = src[0]; by1[i] = src[1]; bx2[i] = src[2]; by2[i] = src[3];
    bsc[i] = src[4]; blb[i] = src[5]; bval[i] = 1;
  }
  __syncthreads();
  float sf = sfp[n];
  for (int it = 0; it < 100; ++it) {
    float best = -1.f; int bi = -1;
    for (int i = tid; i < cnt; i += 256)
      if (bval[i] && bsc[i] > best) { best = bsc[i]; bi = i; }
    rs[tid] = best; ri[tid] = bi;
    __syncthreads();
    for (int off = 128; off > 0; off >>= 1) {
      if (tid < off && rs[tid + off] > rs[tid]) { rs[tid] = rs[tid + off]; ri[tid] = ri[tid + off]; }
      __syncthreads();
    }
    int wi = ri[0]; float wsc = rs[0];
    if (wi < 0) break;                    // uniform: no valid left, rows stay 0
    if (tid == 0) {
      float* o = out + (size_t)(n * 100 + it) * 6;
      o[0] = bx1[wi] / sf; o[1] = by1[wi] / sf;
      o[2] = bx2[wi] / sf; o[3] = by2[wi] / sf;
      o[4] = wsc;          o[5] = blb[wi];
    }
    // suppress IoU > 0.6 on class-offset boxes (offset adds to all 4 coords)
    float ofw = blb[wi] * IMG_F;
    float wx1 = bx1[wi] + ofw, wy1 = by1[wi] + ofw;
    float wx2 = bx2[wi] + ofw, wy2 = by2[wi] + ofw;
    float wa = (wx2 - wx1) * (wy2 - wy1);
    for (int i = tid; i < cnt; i += 256) {
      if (bval[i]) {
        float o2 = blb[i] * IMG_F;
        float x1 = bx1[i] + o2, y1 = by1[i] + o2, x2 = bx2[i] + o2, y2 = by2[i] + o2;
        float iw = fmaxf(fminf(wx2, x2) - fmaxf(wx1, x1), 0.f);
        float ih = fmaxf(fminf(wy2, y2) - fmaxf(wy1, y1), 0.f);
        float inter = iw * ih;
        float area = (x2 - x1) * (y2 - y1);
        float iou = inter / (wa + area - inter + 1e-7f);
        if (iou > 0.6f) bval[i] = 0;
      }
    }
    if (tid == 0) bval[wi] = 0;
    __syncthreads();
  }
}

// ---------------------------------------------------------------------------
extern "C" void kernel_launch(void* const* d_in, const int* in_sizes, int n_in,
                              void* d_out, int out_size, void* d_ws, size_t ws_size,
                              hipStream_t stream) {
  // setup_inputs() dict order: f0,w0,b0, f1,w1,b1, f2,w2,b2, scale_factors
  const float* f0 = (const float*)d_in[0];
  const float* w0 = (const float*)d_in[1];
  const float* b0 = (const float*)d_in[2];
  const float* f1 = (const float*)d_in[3];
  const float* w1 = (const float*)d_in[4];
  const float* b1 = (const float*)d_in[5];
  const float* f2 = (const float*)d_in[6];
  const float* w2 = (const float*)d_in[7];
  const float* b2 = (const float*)d_in[8];
  const float* sf = (const float*)d_in[9];
  float* out = (float*)d_out;
  float* ws  = (float*)d_ws;    // needs ~1.8 MB

  ka_init <<<1344, 256, 0, stream>>>(ws, out, w0, w1, w2);
  kb_obj  <<<700,  256, 0, stream>>>(f0, f1, f2, w0, w1, w2, b0, b1, b2, ws);
  kc_score<<<128,  256, 0, stream>>>(f0, f1, f2, b0, b1, b2, ws);
  kd_nms  <<<8,    256, 0, stream>>>(ws, out, sf);
}